// Round 1
// baseline (272.528 us; speedup 1.0000x reference)
//
#include <hip/hip_runtime.h>

#define XN 16
#define XC 64
#define XT 30
#define XH 64
#define XW 44
#define OUTW 22
#define ATTH 32
#define OUTH 48
#define CB 2
#define NTHR 704   // 32 * 22

// LDS layout (float offsets), all 16B-aligned
#define XS_OFF   0        // xs  [CB][64*44]  = 5632
#define A1_OFF   5632     // a1t [CB][22*68]  = 2992  (transposed, padded stride 68)
#define FY_OFF   8624     // fy  [32*68]      = 2176  (padded stride 68)
#define FX_OFF   10800    // fx  [22*44]      = 968
#define FT_OFF   11768    // ft  [30*30]      = 900
#define LDS_FLOATS 12668

__global__ __launch_bounds__(NTHR) void glimpse_kernel(
    const float* __restrict__ x,
    const float* __restrict__ p_dt, const float* __restrict__ p_dx,
    const float* __restrict__ p_dy, const float* __restrict__ p_ls2,
    const float* __restrict__ p_ldt, const float* __restrict__ p_ld,
    const float* __restrict__ p_lg, float* __restrict__ out)
{
    const int tid = threadIdx.x;
    const int bid = blockIdx.x;
    const int n  = bid >> 5;           // / 32 c-groups
    const int c0 = (bid & 31) * CB;

    __shared__ __align__(16) float lds[LDS_FLOATS];
    float* xs  = lds + XS_OFF;
    float* a1t = lds + A1_OFF;
    float* fy  = lds + FY_OFF;
    float* fx  = lds + FX_OFF;
    float* ft  = lds + FT_OFF;

    // per-n scalars (uniform across block)
    const float dt_     = tanhf(p_dt[n]) * 15.f + 15.f;   // T/2, anchor_t
    const float dx_     = tanhf(p_dx[n]) * 22.f + 22.f;   // IN_W/2, anchor_x
    const float dy_     = tanhf(p_dy[n]) * 32.f + 32.f;   // IN_H/2, anchor_y
    const float inv2s   = 1.f / (2.f * expf(p_ls2[n]));
    const float delta_t = expf(p_ldt[n]);
    const float delta   = expf(p_ld[n]);
    const float gamma   = 1.f / (1.f + expf(-p_lg[n]));

    // filterbank rows: 84 rows, one thread each (one-time cost)
    if (tid < 84) {
        float mu; float* row; int len;
        if (tid < 30)      { mu = dt_ + (float)(tid - 15) * delta_t; row = ft + tid * 30;      len = 30; }
        else if (tid < 52) { int a = tid - 30; mu = dx_ + (float)(a - 11) * delta; row = fx + a * 44; len = 44; }
        else               { int b = tid - 52; mu = dy_ + (float)(b - 16) * delta; row = fy + b * 68; len = 64; }
        float sum = 0.f;
        for (int j = 0; j < len; ++j) {
            float d = (float)j - mu;
            float e = expf(-d * d * inv2s);
            row[j] = e; sum += e;
        }
        float inv = 1.f / fmaxf(sum, 1e-8f);
        for (int j = 0; j < len; ++j) row[j] *= inv;
    }
    __syncthreads();

    const int g = tid / 22;        // h-group / b index, 0..31
    const int a = tid - g * 22;    // output-w index, 0..21

    float acc0[XT], acc1[XT];
    #pragma unroll
    for (int s = 0; s < XT; ++s) { acc0[s] = 0.f; acc1[s] = 0.f; }

    const float4* fx4 = (const float4*)fx;
    const float4* fy4 = (const float4*)fy;
    const float4* a14 = (const float4*)a1t;
    const size_t xbase = (size_t)(n * XC + c0) * (XT * XH * XW);

    for (int t = 0; t < XT; ++t) {
        // ---- stage x slices (2 c's, 2816 floats each = 704 float4 = 1/thread)
        {
            const float* s0 = x + xbase + (size_t)t * (XH * XW);
            const float* s1 = s0 + (size_t)(XT * XH * XW);
            *(float4*)(xs + tid * 4)        = *(const float4*)(s0 + tid * 4);
            *(float4*)(xs + 2816 + tid * 4) = *(const float4*)(s1 + tid * 4);
        }
        __syncthreads();

        // ---- phase 2: A1[c][h][a] = sum_w xs[c][h][w] * Fx[a][w], h in {g, g+32}
        float s00 = 0.f, s01 = 0.f, s10 = 0.f, s11 = 0.f;
        {
            const float4* xr0 = (const float4*)xs + g * 11;
            const float4* xr1 = (const float4*)xs + (g + 32) * 11;
            #pragma unroll
            for (int wc = 0; wc < 11; ++wc) {
                float4 f   = fx4[a * 11 + wc];
                float4 v00 = xr0[wc];
                float4 v01 = xr1[wc];
                float4 v10 = xr0[704 + wc];
                float4 v11 = xr1[704 + wc];
                s00 = fmaf(f.x, v00.x, s00); s00 = fmaf(f.y, v00.y, s00);
                s00 = fmaf(f.z, v00.z, s00); s00 = fmaf(f.w, v00.w, s00);
                s01 = fmaf(f.x, v01.x, s01); s01 = fmaf(f.y, v01.y, s01);
                s01 = fmaf(f.z, v01.z, s01); s01 = fmaf(f.w, v01.w, s01);
                s10 = fmaf(f.x, v10.x, s10); s10 = fmaf(f.y, v10.y, s10);
                s10 = fmaf(f.z, v10.z, s10); s10 = fmaf(f.w, v10.w, s10);
                s11 = fmaf(f.x, v11.x, s11); s11 = fmaf(f.y, v11.y, s11);
                s11 = fmaf(f.z, v11.z, s11); s11 = fmaf(f.w, v11.w, s11);
            }
        }
        // write transposed: a1t[c][a*68 + h]
        a1t[a * 68 + g]             = s00;
        a1t[a * 68 + g + 32]        = s01;
        a1t[1496 + a * 68 + g]      = s10;
        a1t[1496 + a * 68 + g + 32] = s11;
        __syncthreads();

        // ---- phase 3: A2[c][b][a] = sum_h Fy[b][h] * A1[c][h][a]   (b == g)
        float a20 = 0.f, a21 = 0.f;
        #pragma unroll
        for (int hc = 0; hc < 16; ++hc) {
            float4 f  = fy4[g * 17 + hc];
            float4 v0 = a14[a * 17 + hc];
            float4 v1 = a14[374 + a * 17 + hc];
            a20 = fmaf(f.x, v0.x, a20); a20 = fmaf(f.y, v0.y, a20);
            a20 = fmaf(f.z, v0.z, a20); a20 = fmaf(f.w, v0.w, a20);
            a21 = fmaf(f.x, v1.x, a21); a21 = fmaf(f.y, v1.y, a21);
            a21 = fmaf(f.z, v1.z, a21); a21 = fmaf(f.w, v1.w, a21);
        }

        // ---- phase 4: acc[s] += Ft[s][t] * A2   (Ft read is wave-uniform broadcast)
        #pragma unroll
        for (int s = 0; s < XT; ++s) {
            float fts = ft[s * 30 + t];
            acc0[s] = fmaf(fts, a20, acc0[s]);
            acc1[s] = fmaf(fts, a21, acc1[s]);
        }
    }

    // ---- epilogue: out[n,c,s, b+8, a]; thread tid <-> element 176+tid (coalesced)
    const size_t obase = (size_t)(n * XC + c0) * (XT * OUTH * OUTW);
    #pragma unroll
    for (int s = 0; s < XT; ++s) {
        float* o0 = out + obase + (size_t)s * (OUTH * OUTW);
        float* o1 = o0 + (size_t)(XT * OUTH * OUTW);
        o0[176 + tid] = gamma * acc0[s];
        o1[176 + tid] = gamma * acc1[s];
        if (tid < 176) {
            o0[tid] = 0.f; o0[880 + tid] = 0.f;
            o1[tid] = 0.f; o1[880 + tid] = 0.f;
        }
    }
}

extern "C" void kernel_launch(void* const* d_in, const int* in_sizes, int n_in,
                              void* d_out, int out_size, void* d_ws, size_t ws_size,
                              hipStream_t stream) {
    const float* x   = (const float*)d_in[0];
    const float* dt  = (const float*)d_in[1];
    const float* dx  = (const float*)d_in[2];
    const float* dy  = (const float*)d_in[3];
    const float* ls2 = (const float*)d_in[4];
    const float* ldt = (const float*)d_in[5];
    const float* ld  = (const float*)d_in[6];
    const float* lg  = (const float*)d_in[7];
    float* out = (float*)d_out;

    glimpse_kernel<<<dim3(XN * (XC / CB)), dim3(NTHR), 0, stream>>>(
        x, dt, dx, dy, ls2, ldt, ld, lg, out);
}

// Round 2
// 190.620 us; speedup vs baseline: 1.4297x; 1.4297x over previous
//
#include <hip/hip_runtime.h>

#define XN 16
#define XC 64
#define XT 30
#define XH 64
#define XW 44
#define OUTW 22
#define ATTH 32
#define OUTH 48

#define NTHR 704          // 11 waves
#define RW 7              // task-waves per round (LDS-budget limited)
#define NTASK 60          // 2 c * 30 t per block
#define NROUND 9          // ceil(60/7)

// d_ws layout per n (float units), all 16B-aligned
#define FXT_OFF 0         // fxt[w=44][a=22] f32   (Fx transposed)
#define FTT_OFF 968       // ftt[t=30][s=30] f32   (Ft transposed)
#define FYB_OFF 1868      // fyb[b=32][h=64] bf16  (2048 u16 = 1024 f32 slots)
#define NS      2944

// LDS budget (bytes): per task-wave region = xbuf(64*44 bf16 = 5632B),
// a1t (22 rows * 72 bf16 = 3168B) aliases xbuf. a2buf bf16 after.
#define WREG_B 5632
#define A2_OFF_B (RW * WREG_B)        // 39424
#define A2_STRIDE 736                 // u16 per task: 32*23
#define LDS_B (A2_OFF_B + RW * A2_STRIDE * 2)   // 49728 < 64KB

typedef short s8v __attribute__((ext_vector_type(8)));
typedef float f32x16 __attribute__((ext_vector_type(16)));

__device__ __forceinline__ unsigned int pkbf(float lo, float hi) {
    unsigned int a = __float_as_uint(lo);
    unsigned int b = __float_as_uint(hi);
    a = (a + 0x7FFFu + ((a >> 16) & 1u)) >> 16;
    b = (b + 0x7FFFu + ((b >> 16) & 1u)) & 0xFFFF0000u;
    return a | b;
}
__device__ __forceinline__ unsigned short rne16(float v) {
    unsigned int u = __float_as_uint(v);
    return (unsigned short)((u + 0x7FFFu + ((u >> 16) & 1u)) >> 16);
}
__device__ __forceinline__ float bf2f(unsigned short u) {
    return __uint_as_float(((unsigned int)u) << 16);
}

// ---------------- prep: filterbanks -> d_ws ----------------
__global__ void prep_kernel(const float* __restrict__ dtp, const float* __restrict__ dxp,
                            const float* __restrict__ dyp, const float* __restrict__ ls2,
                            const float* __restrict__ ldt, const float* __restrict__ ldp,
                            float* __restrict__ ws)
{
    int n = blockIdx.x;
    int r = threadIdx.x;
    float dt_ = tanhf(dtp[n]) * 15.f + 15.f;
    float dx_ = tanhf(dxp[n]) * 22.f + 22.f;
    float dy_ = tanhf(dyp[n]) * 32.f + 32.f;
    float inv2s = 1.f / (2.f * expf(ls2[n]));
    float delta_t = expf(ldt[n]);
    float delta = expf(ldp[n]);
    float* wn = ws + (size_t)n * NS;
    float e[64];
    if (r < 30) {                 // Ft row s=r over t=0..29, store ftt[t][s]
        float mu = dt_ + (float)(r - 15) * delta_t;
        float sum = 0.f;
        for (int t = 0; t < 30; ++t) { float d = (float)t - mu; float v = expf(-d*d*inv2s); e[t] = v; sum += v; }
        float inv = 1.f / fmaxf(sum, 1e-8f);
        for (int t = 0; t < 30; ++t) wn[FTT_OFF + t*30 + r] = e[t] * inv;
    } else if (r < 52) {          // Fx row a over w, store fxt[w][a]
        int a = r - 30;
        float mu = dx_ + (float)(a - 11) * delta;
        float sum = 0.f;
        for (int w = 0; w < 44; ++w) { float d = (float)w - mu; float v = expf(-d*d*inv2s); e[w] = v; sum += v; }
        float inv = 1.f / fmaxf(sum, 1e-8f);
        for (int w = 0; w < 44; ++w) wn[FXT_OFF + w*22 + a] = e[w] * inv;
    } else if (r < 84) {          // Fy row b over h, store bf16 fyb[b][h]
        int b = r - 52;
        float mu = dy_ + (float)(b - 16) * delta;
        float sum = 0.f;
        for (int h = 0; h < 64; ++h) { float d = (float)h - mu; float v = expf(-d*d*inv2s); e[h] = v; sum += v; }
        float inv = 1.f / fmaxf(sum, 1e-8f);
        unsigned short* fyb = (unsigned short*)(wn + FYB_OFF);
        for (int h = 0; h < 64; ++h) fyb[b*64 + h] = rne16(e[h] * inv);
    }
}

// ---------------- main fused kernel ----------------
__global__ __launch_bounds__(NTHR) void glimpse_kernel(
    const float* __restrict__ x, const float* __restrict__ ws,
    const float* __restrict__ p_lg, float* __restrict__ out)
{
    const int tid = threadIdx.x;
    const int bid = blockIdx.x;
    const int n  = bid >> 5;
    const int c0 = (bid & 31) * 2;

    __shared__ __align__(16) unsigned char lds[LDS_B];

    const float* wn = ws + (size_t)n * NS;
    const float gamma = 1.f / (1.f + expf(-p_lg[n]));

    const int wv = tid >> 6;
    const int l  = tid & 63;
    // phase-4 / epilogue mapping
    const int g4 = tid / 22;
    const int a4 = tid - g4 * 22;

    // Fy A-frags (const per n): lane row=l&31, k = kt*16 + 8*(l>>5) + i
    const uint4* fybv = (const uint4*)(wn + FYB_OFF);
    const int fybase = (l & 31) * 8 + (l >> 5);
    uint4 afr[4];
    #pragma unroll
    for (int kt = 0; kt < 4; ++kt) afr[kt] = fybv[fybase + kt * 2];

    float acc0[XT], acc1[XT];
    #pragma unroll
    for (int s = 0; s < XT; ++s) { acc0[s] = 0.f; acc1[s] = 0.f; }

    for (int r = 0; r < NROUND; ++r) {
        const int tk = r * RW + wv;
        if (wv < RW && tk < NTASK) {
            const int c = tk & 1, t = tk >> 1;
            // ---- load x slice (64x44 f32) coalesced
            const float4* src = (const float4*)(x + (((size_t)(n * XC + c0 + c)) * XT + t) * (XH * XW));
            float4 v[11];
            #pragma unroll
            for (int k = 0; k < 11; ++k) v[k] = src[k * 64 + l];
            // ---- stage as bf16 pairs, row-major [h][w/2] words (wave-private)
            unsigned int* xb = (unsigned int*)(lds + wv * WREG_B);
            #pragma unroll
            for (int k = 0; k < 11; ++k) {
                int f  = (k * 64 + l) * 4;
                int h  = f / 44;
                int w0 = f - h * 44;
                int wi = h * 22 + (w0 >> 1);
                xb[wi]     = pkbf(v[k].x, v[k].y);
                xb[wi + 1] = pkbf(v[k].z, v[k].w);
            }
            // ---- transpose read: lane = h = l holds its packed row
            unsigned int xr[22];
            #pragma unroll
            for (int j = 0; j < 22; ++j) xr[j] = xb[l * 22 + j];
            // ---- phase 2: acc[a] = sum_w Fx[a][w]*x[h][w]  (Fx via SGPR s_loads)
            float acc[22];
            #pragma unroll
            for (int a = 0; a < 22; ++a) acc[a] = 0.f;
            const float* fxt = wn + FXT_OFF;
            #pragma unroll
            for (int j = 0; j < 22; ++j) {
                float xlo = __uint_as_float(xr[j] << 16);
                float xhi = __uint_as_float(xr[j] & 0xFFFF0000u);
                const float* f0 = fxt + (2 * j) * 22;   // rows w=2j, w=2j+1 contiguous
                #pragma unroll
                for (int a = 0; a < 22; ++a)
                    acc[a] = fmaf(f0[a], xlo, fmaf(f0[22 + a], xhi, acc[a]));
            }
            // ---- A1 -> LDS bf16 transposed [a][h], stride 72 (aliases xbuf; wave-local order ok)
            unsigned short* a1t = (unsigned short*)(lds + wv * WREG_B);
            #pragma unroll
            for (int a = 0; a < 22; ++a) a1t[a * 72 + l] = rne16(acc[a]);
            // ---- phase 3: A2[b][a] = Fy(32x64) . A1(64x22) via 4x mfma 32x32x16 bf16
            const int al   = l & 31;
            const int arow = (al < 22) ? al : 0;
            const int koff = 8 * (l >> 5);
            f32x16 D;
            #pragma unroll
            for (int q = 0; q < 16; ++q) D[q] = 0.f;
            #pragma unroll
            for (int kt = 0; kt < 4; ++kt) {
                s8v bfr = *(const s8v*)(a1t + arow * 72 + kt * 16 + koff);
                D = __builtin_amdgcn_mfma_f32_32x32x16_bf16(*(const s8v*)&afr[kt], bfr, D, 0, 0, 0);
            }
            // ---- A2 -> a2buf bf16 [task][b][23]  (D: col=lane&31=a, row b=(q&3)+8(q>>2)+4(l>>5))
            unsigned short* a2 = (unsigned short*)(lds + A2_OFF_B) + wv * A2_STRIDE;
            if (al < 22) {
                #pragma unroll
                for (int q = 0; q < 16; ++q) {
                    int b = (q & 3) + 8 * (q >> 2) + 4 * (l >> 5);
                    a2[b * 23 + al] = rne16(D[q]);
                }
            }
        }
        __syncthreads();
        // ---- phase 4: acc[s] += Ft[s][t] * A2  (Ft via SGPR s_loads)
        {
            int rem = NTASK - r * RW;
            int nw = rem < RW ? rem : RW;
            const unsigned short* a2r = (const unsigned short*)(lds + A2_OFF_B);
            for (int w = 0; w < nw; ++w) {
                int tk2 = r * RW + w;
                int c = tk2 & 1, t = tk2 >> 1;
                float vv = bf2f(a2r[w * A2_STRIDE + g4 * 23 + a4]);
                const float* ft = wn + FTT_OFF + t * 30;
                if (c == 0) {
                    #pragma unroll
                    for (int s = 0; s < XT; ++s) acc0[s] = fmaf(ft[s], vv, acc0[s]);
                } else {
                    #pragma unroll
                    for (int s = 0; s < XT; ++s) acc1[s] = fmaf(ft[s], vv, acc1[s]);
                }
            }
        }
        __syncthreads();
    }

    // ---- epilogue: out[n,c,s,b+8,a]; element 176+tid per (c,s) slice, coalesced
    const size_t obase = (size_t)(n * XC + c0) * (XT * OUTH * OUTW);
    #pragma unroll
    for (int s = 0; s < XT; ++s) {
        float* o0 = out + obase + (size_t)s * (OUTH * OUTW);
        float* o1 = o0 + (size_t)XT * (OUTH * OUTW);
        o0[176 + tid] = gamma * acc0[s];
        o1[176 + tid] = gamma * acc1[s];
        if (tid < 176) {
            o0[tid] = 0.f; o0[880 + tid] = 0.f;
            o1[tid] = 0.f; o1[880 + tid] = 0.f;
        }
    }
}

extern "C" void kernel_launch(void* const* d_in, const int* in_sizes, int n_in,
                              void* d_out, int out_size, void* d_ws, size_t ws_size,
                              hipStream_t stream) {
    const float* x   = (const float*)d_in[0];
    const float* dt  = (const float*)d_in[1];
    const float* dx  = (const float*)d_in[2];
    const float* dy  = (const float*)d_in[3];
    const float* ls2 = (const float*)d_in[4];
    const float* ldt = (const float*)d_in[5];
    const float* ld  = (const float*)d_in[6];
    const float* lg  = (const float*)d_in[7];
    float* out = (float*)d_out;
    float* ws  = (float*)d_ws;   // needs 16*2944*4 = 188KB

    prep_kernel<<<dim3(XN), dim3(96), 0, stream>>>(dt, dx, dy, ls2, ldt, ld, ws);
    glimpse_kernel<<<dim3(XN * 32), dim3(NTHR), 0, stream>>>(x, ws, lg, out);
}

// Round 4
// 112.690 us; speedup vs baseline: 2.4184x; 1.6915x over previous
//
#include <hip/hip_runtime.h>
#include <hip/hip_fp16.h>

#define XN 16
#define XC 64
#define XT 30
#define XH 64
#define XW 44
#define OUTW 22
#define ATTH 32
#define OUTH 48
#define SLICE (XH*XW)        // 2816
#define OSLICE (OUTH*OUTW)   // 1056

// ws per-n layout (u32 units): f16 MFMA fragments, lane-indexed
#define WS_FX 0                    // [3][64][4]
#define WS_FY (3*64*4)             // 768: [4][64][4]
#define WS_FT (WS_FY + 4*64*4)     // 1792: [2][64][4]
#define WS_N  (WS_FT + 2*64*4)     // 2304 u32 per n

typedef _Float16 f16;
typedef f16 f16x8 __attribute__((ext_vector_type(8)));
typedef float f32x16 __attribute__((ext_vector_type(16)));
typedef float f32x4 __attribute__((ext_vector_type(4)));

__device__ __forceinline__ unsigned int PK(float a, float b) {
    return __builtin_bit_cast(unsigned int, __builtin_amdgcn_cvt_pkrtz(a, b));
}
__device__ __forceinline__ f32x16 MF(uint4 a, uint4 b, f32x16 c) {
    return __builtin_amdgcn_mfma_f32_32x32x16_f16(
        __builtin_bit_cast(f16x8, a), __builtin_bit_cast(f16x8, b), c, 0, 0, 0);
}
__device__ __forceinline__ f32x16 ZF() {
    f32x16 z;
    #pragma unroll
    for (int i = 0; i < 16; ++i) z[i] = 0.f;
    return z;
}

// ---------------- prep: filterbank fragments -> d_ws ----------------
__global__ void prep_kernel(const float* __restrict__ dtp, const float* __restrict__ dxp,
                            const float* __restrict__ dyp, const float* __restrict__ ls2,
                            const float* __restrict__ ldt, const float* __restrict__ ldp,
                            unsigned int* __restrict__ ws)
{
    __shared__ float fx[22][44];
    __shared__ float fy[32][64];
    __shared__ float ft[30][32];
    const int n = blockIdx.x;
    const int r = threadIdx.x;   // 96 threads
    const float dt_ = tanhf(dtp[n]) * 15.f + 15.f;
    const float dx_ = tanhf(dxp[n]) * 22.f + 22.f;
    const float dy_ = tanhf(dyp[n]) * 32.f + 32.f;
    const float inv2s = 1.f / (2.f * expf(ls2[n]));
    const float delta_t = expf(ldt[n]);
    const float delta = expf(ldp[n]);

    if (r < 30) {
        float mu = dt_ + (float)(r - 15) * delta_t;
        float e[30]; float sum = 0.f;
        for (int t = 0; t < 30; ++t) { float d = (float)t - mu; float v = expf(-d*d*inv2s); e[t] = v; sum += v; }
        float inv = 1.f / fmaxf(sum, 1e-8f);
        for (int t = 0; t < 30; ++t) ft[r][t] = e[t] * inv;
        ft[r][30] = 0.f; ft[r][31] = 0.f;
    } else if (r < 52) {
        int a = r - 30;
        float mu = dx_ + (float)(a - 11) * delta;
        float e[44]; float sum = 0.f;
        for (int w = 0; w < 44; ++w) { float d = (float)w - mu; float v = expf(-d*d*inv2s); e[w] = v; sum += v; }
        float inv = 1.f / fmaxf(sum, 1e-8f);
        for (int w = 0; w < 44; ++w) fx[a][w] = e[w] * inv;
    } else if (r < 84) {
        int b = r - 52;
        float mu = dy_ + (float)(b - 16) * delta;
        float e[64]; float sum = 0.f;
        for (int h = 0; h < 64; ++h) { float d = (float)h - mu; float v = expf(-d*d*inv2s); e[h] = v; sum += v; }
        float inv = 1.f / fmaxf(sum, 1e-8f);
        for (int h = 0; h < 64; ++h) fy[b][h] = e[h] * inv;
    }
    __syncthreads();

    if (r < 64) {
        const int al = r & 31, hf = r >> 5;
        unsigned int* wn = ws + n * WS_N;
        // Fx B-frag for MFMA1: col a = al, k = w
        #pragma unroll
        for (int kt = 0; kt < 3; ++kt) {
            int w0 = kt*16 + 8*hf;
            float v[8];
            #pragma unroll
            for (int i = 0; i < 8; ++i) { int w = w0 + i; v[i] = (al < 22 && w < 44) ? fx[al][w] : 0.f; }
            #pragma unroll
            for (int j = 0; j < 4; ++j) {
                unsigned int lo = __half_as_ushort(__float2half_rn(v[2*j]));
                unsigned int hi = __half_as_ushort(__float2half_rn(v[2*j+1]));
                wn[WS_FX + (kt*64 + r)*4 + j] = lo | (hi << 16);
            }
        }
        // Fy A-frag for MFMA2: row b = al, k = h
        #pragma unroll
        for (int kt = 0; kt < 4; ++kt) {
            int h0 = kt*16 + 8*hf;
            float v[8];
            #pragma unroll
            for (int i = 0; i < 8; ++i) v[i] = fy[al][h0 + i];
            #pragma unroll
            for (int j = 0; j < 4; ++j) {
                unsigned int lo = __half_as_ushort(__float2half_rn(v[2*j]));
                unsigned int hi = __half_as_ushort(__float2half_rn(v[2*j+1]));
                wn[WS_FY + (kt*64 + r)*4 + j] = lo | (hi << 16);
            }
        }
        // Ft A-frag for MFMA3: row s = al, k = t
        #pragma unroll
        for (int kt = 0; kt < 2; ++kt) {
            int t0 = kt*16 + 8*hf;
            float v[8];
            #pragma unroll
            for (int i = 0; i < 8; ++i) v[i] = (al < 30) ? ft[al][t0 + i] : 0.f;
            #pragma unroll
            for (int j = 0; j < 4; ++j) {
                unsigned int lo = __half_as_ushort(__float2half_rn(v[2*j]));
                unsigned int hi = __half_as_ushort(__float2half_rn(v[2*j+1]));
                wn[WS_FT + (kt*64 + r)*4 + j] = lo | (hi << 16);
            }
        }
    }
}

// ---------------- main kernel: one block = one (n,c) ----------------
__global__ __launch_bounds__(256, 2) void glimpse_kernel(
    const float* __restrict__ x, const unsigned int* __restrict__ ws,
    const float* __restrict__ p_lg, float* __restrict__ out)
{
    const int tid = threadIdx.x;
    const int n = blockIdx.x >> 6, c = blockIdx.x & 63;
    const int wv = tid >> 6, l = tid & 63;
    const int al = l & 31, hf = l >> 5;

    __shared__ unsigned int a1t[4][32*34];   // per-wave [a][34 u32] (h pairs)
    __shared__ unsigned int a2t[704*17];     // [ba][17 u32] = [ba][34 f16 t-slots]

    // zero the t=30..33 pad columns (disjoint from hop2's t<30 writes)
    for (int r = tid; r < 704; r += 256) { a2t[r*17 + 15] = 0u; a2t[r*17 + 16] = 0u; }

    // zero-pad output rows (h<8, h>=40), nontemporal
    const size_t obase = (size_t)(n*XC + c) * (XT*OSLICE);
    {
        f32x4 z4 = {0.f, 0.f, 0.f, 0.f};
        f32x4* out4 = (f32x4*)(out + obase);
        #pragma unroll
        for (int k2 = 0; k2 < 11; ++k2) {
            int idx = tid + k2*256;
            if (idx < 2640) {
                int s = idx / 88;
                int rr = idx - s*88;
                int j = (rr < 44) ? rr : (rr + 176);
                __builtin_nontemporal_store(z4, out4 + s*264 + j);
            }
        }
    }

    // preload filter fragments
    const unsigned int* wn = ws + n * WS_N;
    uint4 fxf[3], fyf[4], ftf[2];
    #pragma unroll
    for (int kt = 0; kt < 3; ++kt) fxf[kt] = *(const uint4*)(wn + WS_FX + (kt*64 + l)*4);
    #pragma unroll
    for (int kt = 0; kt < 4; ++kt) fyf[kt] = *(const uint4*)(wn + WS_FY + (kt*64 + l)*4);
    #pragma unroll
    for (int kt = 0; kt < 2; ++kt) ftf[kt] = *(const uint4*)(wn + WS_FT + (kt*64 + l)*4);

    const float gamma = 1.f / (1.f + expf(-p_lg[n]));

    unsigned int* myA1 = &a1t[wv][0];
    unsigned short* a2t16 = (unsigned short*)a2t;
    const float* xc = x + (size_t)(n*XC + c) * (XT*SLICE);

    // waves own disjoint t's: no barriers in this loop
    #pragma unroll 2
    for (int t = wv; t < XT; t += 4) {
        const float* xs = xc + (size_t)t * SLICE;
        f32x16 D0 = ZF(), D1m = ZF(), D2 = ZF();
        // MFMA1: A1[h][a] = sum_w x[h][w] * FxT[w][a]; x frags direct from global
        #pragma unroll
        for (int mt = 0; mt < 2; ++mt) {
            const float* rb = xs + (mt*32 + al)*44;
            float4 A0 = *(const float4*)(rb + 8*hf);
            float4 A1v = *(const float4*)(rb + 8*hf + 4);
            float4 B0 = *(const float4*)(rb + 16 + 8*hf);
            float4 B1 = *(const float4*)(rb + 16 + 8*hf + 4);
            float4 C0 = *(const float4*)(rb + 32 + 8*hf);     // hf=1 -> w40..43
            float4 C1 = (hf == 0) ? *(const float4*)(rb + 36) : make_float4(0.f,0.f,0.f,0.f);
            uint4 u0 = make_uint4(PK(A0.x,A0.y), PK(A0.z,A0.w), PK(A1v.x,A1v.y), PK(A1v.z,A1v.w));
            uint4 u1 = make_uint4(PK(B0.x,B0.y), PK(B0.z,B0.w), PK(B1.x,B1.y), PK(B1.z,B1.w));
            uint4 u2 = make_uint4(PK(C0.x,C0.y), PK(C0.z,C0.w), PK(C1.x,C1.y), PK(C1.z,C1.w));
            if (mt == 0) {
                D0 = MF(u0, fxf[0], D0); D0 = MF(u1, fxf[1], D0); D0 = MF(u2, fxf[2], D0);
            } else {
                D1m = MF(u0, fxf[0], D1m); D1m = MF(u1, fxf[1], D1m); D1m = MF(u2, fxf[2], D1m);
            }
        }
        // hop1: D (col a, rows h) -> a1t[a][h/2] as f16 pairs
        #pragma unroll
        for (int j = 0; j < 8; ++j) {
            int wofs = (j & 1) + 4*(j >> 1) + 2*hf;
            myA1[al*34 + wofs]      = PK(D0[2*j],  D0[2*j+1]);
            myA1[al*34 + wofs + 16] = PK(D1m[2*j], D1m[2*j+1]);
        }
        // MFMA2: A2[b][a] = sum_h Fy[b][h] * A1[h][a]
        #pragma unroll
        for (int kt = 0; kt < 4; ++kt) {
            int base = al*34 + kt*8 + 4*hf;
            uint4 bw;
            bw.x = myA1[base]; bw.y = myA1[base+1]; bw.z = myA1[base+2]; bw.w = myA1[base+3];
            D2 = MF(fyf[kt], bw, D2);
        }
        // hop2: D2 (col a, rows b) -> a2t[b*22+a][t] f16
        if (al < 22) {
            #pragma unroll
            for (int q = 0; q < 16; ++q) {
                int b = (q & 3) + 8*(q >> 2) + 4*hf;
                unsigned short hv = __builtin_bit_cast(unsigned short, (_Float16)D2[q]);
                a2t16[(b*22 + al)*34 + t] = hv;
            }
        }
    }
    __syncthreads();

    // MFMA3: G[s][ba] = sum_t Ft[s][t] * A2t[ba][t]
    #pragma unroll 2
    for (int nt = wv; nt < 22; nt += 4) {
        int ba = nt*32 + al;
        f32x16 D3 = ZF();
        #pragma unroll
        for (int kt = 0; kt < 2; ++kt) {
            int base = ba*17 + kt*8 + 4*hf;
            uint4 bw;
            bw.x = a2t[base]; bw.y = a2t[base+1]; bw.z = a2t[base+2]; bw.w = a2t[base+3];
            D3 = MF(ftf[kt], bw, D3);
        }
        float* ob = out + obase + 176 + ba;
        #pragma unroll
        for (int q = 0; q < 16; ++q) {
            int s = (q & 3) + 8*(q >> 2) + 4*hf;
            if (s < XT) __builtin_nontemporal_store(gamma * D3[q], ob + s*OSLICE);
        }
    }
}

extern "C" void kernel_launch(void* const* d_in, const int* in_sizes, int n_in,
                              void* d_out, int out_size, void* d_ws, size_t ws_size,
                              hipStream_t stream) {
    const float* x   = (const float*)d_in[0];
    const float* dt  = (const float*)d_in[1];
    const float* dx  = (const float*)d_in[2];
    const float* dy  = (const float*)d_in[3];
    const float* ls2 = (const float*)d_in[4];
    const float* ldt = (const float*)d_in[5];
    const float* ld  = (const float*)d_in[6];
    const float* lg  = (const float*)d_in[7];
    float* out = (float*)d_out;
    unsigned int* ws = (unsigned int*)d_ws;   // 16 * 2304 * 4B = 147 KB

    prep_kernel<<<dim3(XN), dim3(96), 0, stream>>>(dt, dx, dy, ls2, ldt, ld, ws);
    glimpse_kernel<<<dim3(XN * XC), dim3(256), 0, stream>>>(x, ws, lg, out);
}